// Round 7
// baseline (966.836 us; speedup 1.0000x reference)
//
#include <hip/hip_runtime.h>
#include <hip/hip_bf16.h>

#define N_REL 8
#define TM 128
#define TN 128
#define BK 32

typedef unsigned short ushort_t;
typedef unsigned int uint_t;
typedef __attribute__((ext_vector_type(8))) short short8;   // bf16x8 MFMA operand
typedef __attribute__((ext_vector_type(4))) float floatx4;  // MFMA accumulator

static __device__ __forceinline__ ushort_t f2bf(float f) {
    union { float f; unsigned u; } v; v.f = f;
    unsigned r = v.u + 0x7fff + ((v.u >> 16) & 1);
    return (ushort_t)(r >> 16);
}

typedef __attribute__((address_space(1))) void glob_void;
typedef __attribute__((address_space(3))) void lds_void;

static __device__ __forceinline__ void load_lds16(const void* g, void* l) {
    __builtin_amdgcn_global_load_lds((glob_void*)g, (lds_void*)l, 16, 0, 0);
}

// ---------------- sort infrastructure ----------------

__global__ __launch_bounds__(256) void hist_kernel(const int* __restrict__ dst,
                                                   const int* __restrict__ et,
                                                   int* __restrict__ cnt, int E) {
    int e = blockIdx.x * blockDim.x + threadIdx.x;
    if (e < E) atomicAdd(&cnt[dst[e] * N_REL + et[e]], 1);
}

__global__ __launch_bounds__(256) void scan1(const int* __restrict__ cnt,
                                             int* __restrict__ off,
                                             int* __restrict__ bsum, int nk) {
    __shared__ int s[256];
    int t = threadIdx.x;
    int k = blockIdx.x * 256 + t;
    int v = k < nk ? cnt[k] : 0;
    s[t] = v; __syncthreads();
    for (int d = 1; d < 256; d <<= 1) {
        int x = (t >= d) ? s[t - d] : 0;
        __syncthreads(); s[t] += x; __syncthreads();
    }
    if (k < nk) off[k] = s[t] - v;
    if (t == 255) bsum[blockIdx.x] = s[255];
}

__global__ __launch_bounds__(1024) void scan2(int* __restrict__ bsum, int nb) {
    __shared__ int s[1024];
    int t = threadIdx.x;
    int v = t < nb ? bsum[t] : 0;
    s[t] = v; __syncthreads();
    for (int d = 1; d < 1024; d <<= 1) {
        int x = (t >= d) ? s[t - d] : 0;
        __syncthreads(); s[t] += x; __syncthreads();
    }
    if (t < nb) bsum[t] = s[t] - v;
}

__global__ __launch_bounds__(256) void scan3(int* __restrict__ off,
                                             const int* __restrict__ bsum,
                                             int* __restrict__ cursor,
                                             int nk) {
    int k = blockIdx.x * 256 + threadIdx.x;
    if (k >= nk) return;
    int o = off[k] + bsum[k >> 8];
    off[k] = o;
    cursor[k] = o;
}

__global__ __launch_bounds__(256) void scatter_ids(const int* __restrict__ dst,
                                                   const int* __restrict__ et,
                                                   int* __restrict__ cursor,
                                                   int* __restrict__ eid, int E) {
    int e = blockIdx.x * blockDim.x + threadIdx.x;
    if (e < E) {
        int key = dst[e] * N_REL + et[e];
        int pos = atomicAdd(&cursor[key], 1);
        eid[pos] = e;
    }
}

// ---------------- casts ----------------

__global__ __launch_bounds__(256) void cast_bf16(const float* __restrict__ in,
                                                 ushort_t* __restrict__ out, long n) {
    long idx = ((long)blockIdx.x * blockDim.x + threadIdx.x) * 4;
    if (idx + 4 <= n) {
        float4 v = *(const float4*)(in + idx);
        ushort_t o[4] = {f2bf(v.x), f2bf(v.y), f2bf(v.z), f2bf(v.w)};
        *(uint2*)(out + idx) = *(const uint2*)o;
    } else {
        for (; idx < n; ++idx) out[idx] = f2bf(in[idx]);
    }
}

__global__ __launch_bounds__(256) void relu_cast_bf16(const float* __restrict__ in,
                                                      ushort_t* __restrict__ out, long n) {
    long idx = ((long)blockIdx.x * blockDim.x + threadIdx.x) * 4;
    if (idx + 4 <= n) {
        float4 v = *(const float4*)(in + idx);
        ushort_t o[4] = {f2bf(fmaxf(v.x, 0.f)), f2bf(fmaxf(v.y, 0.f)),
                         f2bf(fmaxf(v.z, 0.f)), f2bf(fmaxf(v.w, 0.f))};
        *(uint2*)(out + idx) = *(const uint2*)o;
    } else {
        for (; idx < n; ++idx) out[idx] = f2bf(fmaxf(in[idx], 0.f));
    }
}

// in: [z][K][N] fp32 -> out: [z][N][K] bf16.
__global__ __launch_bounds__(256) void transpose_cast(const float* __restrict__ in,
                                                      ushort_t* __restrict__ out,
                                                      int K, int N) {
    __shared__ float tile[32][33];
    const float* inp = in + (size_t)blockIdx.z * K * N;
    ushort_t* outp = out + (size_t)blockIdx.z * K * N;
    int n0 = blockIdx.x * 32, k0 = blockIdx.y * 32;
    int tx = threadIdx.x & 31, ty = threadIdx.x >> 5;
#pragma unroll
    for (int s = 0; s < 4; ++s)
        tile[ty + 8 * s][tx] = inp[(size_t)(k0 + ty + 8 * s) * N + n0 + tx];
    __syncthreads();
#pragma unroll
    for (int s = 0; s < 4; ++s)
        outp[(size_t)(n0 + ty + 8 * s) * K + k0 + tx] = f2bf(tile[tx][ty + 8 * s]);
}

// ---------------- MFMA GEMM: C[M,N](bf16) = A[M,K] @ Bt[N,K]^T (+bias on cols<bias_n) --------
// XCD-aware swizzle (linear%8 -> contiguous bm chunk per XCD) + XOR-swizzled LDS
// (k-group of row r stored at slot g = kgrp ^ ((r>>1)&3)) so fragment ds_read_b128s
// spread over all 8 bank-groups (2-way only = free).
__global__ __launch_bounds__(256) void gemm_bt(const ushort_t* __restrict__ A,
                                               const ushort_t* __restrict__ Bt,
                                               const float* __restrict__ bias,
                                               int bias_n,
                                               ushort_t* __restrict__ C,
                                               int M, int K, int N) {
    __shared__ union {
        struct { __align__(16) ushort_t A[TM * BK]; __align__(16) ushort_t B[TN * BK]; } st;
        __align__(16) ushort_t c[32 * TN];   // bf16 epilogue staging (8 KB), aliased
    } sh;

    const int t = threadIdx.x;
    const int lane = t & 63;
    const int wave = t >> 6;
    const int wm = wave >> 1, wn = wave & 1;
    const int quad = lane >> 4, l16 = lane & 15;

    const int nx = gridDim.x;
    const int total = nx * gridDim.y;
    int linear = blockIdx.y * nx + blockIdx.x;
    const int nper = total >> 3;
    linear = (linear & 7) * nper + (linear >> 3);
    const int bm = (linear / nx) * TM;
    const int bn = (linear % nx) * TN;
    if (bm >= M) return;

    const int ar = lane >> 2;                              // row within 16-row chunk
    const int ac = (((lane & 3) ^ ((ar >> 1) & 3))) * 8;   // swizzled k-group offset

    floatx4 acc[4][4];
#pragma unroll
    for (int i = 0; i < 4; ++i)
#pragma unroll
        for (int j = 0; j < 4; ++j) acc[i][j] = (floatx4)(0.f);

    const int sw = (l16 >> 1) & 3;                 // read-side swizzle term
    const int colA = ((quad ^ sw) * 8);

    for (int k0 = 0; k0 < K; k0 += BK) {
#pragma unroll
        for (int cc = 0; cc < 2; ++cc) {
            const int c = 2 * wave + cc;
            int gra = bm + c * 16 + ar;
            gra = gra < M ? gra : M - 1;
            load_lds16(A + (size_t)gra * K + k0 + ac, sh.st.A + c * 16 * BK);
            int grb = bn + c * 16 + ar;
            load_lds16(Bt + (size_t)grb * K + k0 + ac, sh.st.B + c * 16 * BK);
        }
        __syncthreads();

        short8 af[4], bfr[4];
#pragma unroll
        for (int i = 0; i < 4; ++i)
            af[i] = *(const short8*)&sh.st.A[(wm * 64 + i * 16 + l16) * BK + colA];
#pragma unroll
        for (int j = 0; j < 4; ++j)
            bfr[j] = *(const short8*)&sh.st.B[(wn * 64 + j * 16 + l16) * BK + colA];
#pragma unroll
        for (int i = 0; i < 4; ++i)
#pragma unroll
            for (int j = 0; j < 4; ++j)
                acc[i][j] = __builtin_amdgcn_mfma_f32_16x16x32_bf16(af[i], bfr[j], acc[i][j], 0, 0, 0);
        __syncthreads();
    }

    // LDS-staged epilogue: 4 passes x 32 rows, full-line 16B/lane stores.
#pragma unroll
    for (int i = 0; i < 4; ++i) {
#pragma unroll
        for (int j = 0; j < 4; ++j) {
            int col = wn * 64 + j * 16 + l16;
            int gcol = bn + col;
            float bv = (bias && gcol < bias_n) ? bias[gcol] : 0.f;
#pragma unroll
            for (int rg = 0; rg < 4; ++rg)
                sh.c[(wm * 16 + quad * 4 + rg) * TN + col] = f2bf(acc[i][j][rg] + bv);
        }
        __syncthreads();
#pragma unroll
        for (int s = 0; s < 2; ++s) {
            int lr = s * 16 + (t >> 4);          // 0..31
            int c8 = (t & 15) * 8;               // col (bf16 units), 16 B chunks
            int grow = bm + (lr >> 4) * 64 + i * 16 + (lr & 15);
            if (grow < M)
                *(uint4*)(C + (size_t)grow * N + bn + c8) = *(const uint4*)&sh.c[lr * TN + c8];
        }
        __syncthreads();
    }
}

// ---------------- fused multi-relation segmented mean (no atomics) ----------------
// One block per dst. H bf16 [*, hstride]; if has_root, cols [0,dim) are the root
// transform of the node itself (always added; final store is a plain write),
// relations occupy cols [root_off + rr*dim, ...). blockDim.x == dim/2.
__global__ __launch_bounds__(256) void segsum_multi(const ushort_t* __restrict__ H,
                                                    float* __restrict__ agg,
                                                    const int* __restrict__ off,
                                                    const int* __restrict__ cnt,
                                                    const int* __restrict__ eid,
                                                    const int* __restrict__ src,
                                                    int rbase, int rcount,
                                                    int dim, int hstride,
                                                    int has_root) {
    int d = blockIdx.x;
    int t = threadIdx.x;
    float a0 = 0.f, a1 = 0.f;
    bool any = false;
    int rel_off = 0;
    if (has_root) {
        uint_t u = *(const uint_t*)(H + (size_t)d * hstride + 2 * t);
        a0 = __uint_as_float(u << 16);
        a1 = __uint_as_float(u & 0xffff0000u);
        any = true;
        rel_off = dim;
    }
    for (int rr = 0; rr < rcount; ++rr) {
        int key = d * N_REL + rbase + rr;
        int c = cnt[key];
        if (c == 0) continue;
        any = true;
        int o = off[key];
        float s0 = 0.f, s1 = 0.f;
        const ushort_t* Hr = H + rel_off + rr * dim + 2 * t;
        for (int k = o; k < o + c; ++k) {
            int e = eid[k];
            int s = src[e];
            uint_t u = *(const uint_t*)(Hr + (size_t)s * hstride);
            s0 += __uint_as_float(u << 16);
            s1 += __uint_as_float(u & 0xffff0000u);
        }
        float inv = 1.0f / (float)c;
        a0 += s0 * inv;
        a1 += s1 * inv;
    }
    if (!any) return;
    float2* p = (float2*)(agg + (size_t)d * dim + 2 * t);
    if (has_root) {
        *p = make_float2(a0, a1);
    } else {
        float2 g = *p;
        g.x += a0;
        g.y += a1;
        *p = g;
    }
}

// ---------------- launcher ----------------

extern "C" void kernel_launch(void* const* d_in, const int* in_sizes, int n_in,
                              void* d_out, int out_size, void* d_ws, size_t ws_size,
                              hipStream_t stream) {
    const float* x     = (const float*)d_in[0];
    const int*   eidx  = (const int*)d_in[1];
    const int*   etype = (const int*)d_in[2];
    const float* W1    = (const float*)d_in[3];
    const float* root1 = (const float*)d_in[4];
    const float* b1    = (const float*)d_in[5];
    const float* W2    = (const float*)d_in[6];
    const float* root2 = (const float*)d_in[7];
    const float* b2    = (const float*)d_in[8];
    float* out = (float*)d_out;

    const int IN_DIM = 1280, HID_DIM = 512, OUT_DIM = 256;
    const int E = in_sizes[2];
    const int N = in_sizes[0] / IN_DIM;
    const int NK = N * N_REL;
    const int* srcs = eidx;
    const int* dsts = eidx + E;

    char* ws = (char*)d_ws;
    size_t offb = 0;
    auto alloc = [&](size_t bytes) { void* p = ws + offb; offb += (bytes + 255) & ~(size_t)255; return p; };
    int*      cnt    = (int*)alloc((size_t)NK * 4);
    int*      off    = (int*)alloc((size_t)NK * 4);
    int*      cursor = (int*)alloc((size_t)NK * 4);
    int*      bsum   = (int*)alloc(1024 * 4);
    int*      eid    = (int*)alloc((size_t)E * 4);
    ushort_t* x_bf   = (ushort_t*)alloc((size_t)N * IN_DIM * 2);   // later reused for hb_bf
    // W1full = [root1^T (512 rows) | W1[0..7]^T (4096 rows)] x 1280, bf16
    ushort_t* W1full = (ushort_t*)alloc((size_t)(HID_DIM + N_REL * HID_DIM) * IN_DIM * 2);
    // W2full = [root2^T (256 rows) | W2[0..7]^T (2048 rows)] x 512, bf16
    ushort_t* W2full = (ushort_t*)alloc((size_t)(OUT_DIM + N_REL * OUT_DIM) * HID_DIM * 2);
    ushort_t* Hb     = (ushort_t*)alloc((size_t)N * 1024 * 2);
    float*    hbuf   = (float*)alloc((size_t)N * HID_DIM * 4);
    ushort_t* hb_bf  = x_bf;  // x_bf dead after layer-1 GEMMs
    (void)ws_size;

    const int nb = (NK + 255) / 256;

    // 1) sort edges by (dst, rel)
    hipMemsetAsync(cnt, 0, (size_t)NK * 4, stream);
    hist_kernel<<<(E + 255) / 256, 256, 0, stream>>>(dsts, etype, cnt, E);
    scan1<<<nb, 256, 0, stream>>>(cnt, off, bsum, NK);
    scan2<<<1, 1024, 0, stream>>>(bsum, nb);
    scan3<<<nb, 256, 0, stream>>>(off, bsum, cursor, NK);
    scatter_ids<<<(E + 255) / 256, 256, 0, stream>>>(dsts, etype, cursor, eid, E);

    // 2) casts / weight transposes (root slice first, then relations)
    {
        long n = (long)N * IN_DIM;
        cast_bf16<<<(unsigned)((n / 4 + 255) / 256), 256, 0, stream>>>(x, x_bf, n);
    }
    transpose_cast<<<dim3(HID_DIM / 32, IN_DIM / 32, 1), 256, 0, stream>>>(root1, W1full, IN_DIM, HID_DIM);
    transpose_cast<<<dim3(HID_DIM / 32, IN_DIM / 32, N_REL), 256, 0, stream>>>(
        W1, W1full + (size_t)HID_DIM * IN_DIM, IN_DIM, HID_DIM);
    transpose_cast<<<dim3(OUT_DIM / 32, HID_DIM / 32, 1), 256, 0, stream>>>(root2, W2full, HID_DIM, OUT_DIM);
    transpose_cast<<<dim3(OUT_DIM / 32, HID_DIM / 32, N_REL), 256, 0, stream>>>(
        W2, W2full + (size_t)OUT_DIM * HID_DIM, HID_DIM, OUT_DIM);

    const int mblk = (N + TM - 1) / TM;
    const int mpad = ((mblk + 7) / 8) * 8;  // total blocks % 8 == 0 -> bijective XCD swizzle

    // 3) layer 1: batch0 = {root, rel0} (N=1024), then {rel1,rel2},{rel3,rel4},{rel5,rel6},{rel7}
    gemm_bt<<<dim3(1024 / TN, mpad), 256, 0, stream>>>(x_bf, W1full, b1, HID_DIM, Hb, N, IN_DIM, 1024);
    segsum_multi<<<N, HID_DIM / 2, 0, stream>>>(Hb, hbuf, off, cnt, eid, srcs, 0, 1, HID_DIM, 1024, 1);
    for (int b = 1; b <= 3; ++b) {
        int r0 = 2 * b - 1;
        gemm_bt<<<dim3(1024 / TN, mpad), 256, 0, stream>>>(
            x_bf, W1full + (size_t)(HID_DIM + r0 * HID_DIM) * IN_DIM, nullptr, 0, Hb, N, IN_DIM, 1024);
        segsum_multi<<<N, HID_DIM / 2, 0, stream>>>(Hb, hbuf, off, cnt, eid, srcs, r0, 2, HID_DIM, 1024, 0);
    }
    gemm_bt<<<dim3(512 / TN, mpad), 256, 0, stream>>>(
        x_bf, W1full + (size_t)(HID_DIM + 7 * HID_DIM) * IN_DIM, nullptr, 0, Hb, N, IN_DIM, 512);
    segsum_multi<<<N, HID_DIM / 2, 0, stream>>>(Hb, hbuf, off, cnt, eid, srcs, 7, 1, HID_DIM, 512, 0);

    {
        long n = (long)N * HID_DIM;
        relu_cast_bf16<<<(unsigned)((n / 4 + 255) / 256), 256, 0, stream>>>(hbuf, hb_bf, n);
    }

    // 4) layer 2: batch0 = {root, rel0..2} (N=1024), then {rel3..6} (N=1024), {rel7} (N=256)
    gemm_bt<<<dim3(1024 / TN, mpad), 256, 0, stream>>>(hb_bf, W2full, b2, OUT_DIM, Hb, N, HID_DIM, 1024);
    segsum_multi<<<N, OUT_DIM / 2, 0, stream>>>(Hb, out, off, cnt, eid, srcs, 0, 3, OUT_DIM, 1024, 1);
    gemm_bt<<<dim3(1024 / TN, mpad), 256, 0, stream>>>(
        hb_bf, W2full + (size_t)(OUT_DIM + 3 * OUT_DIM) * HID_DIM, nullptr, 0, Hb, N, HID_DIM, 1024);
    segsum_multi<<<N, OUT_DIM / 2, 0, stream>>>(Hb, out, off, cnt, eid, srcs, 3, 4, OUT_DIM, 1024, 0);
    gemm_bt<<<dim3(256 / TN, mpad), 256, 0, stream>>>(
        hb_bf, W2full + (size_t)(OUT_DIM + 7 * OUT_DIM) * HID_DIM, nullptr, 0, Hb, N, HID_DIM, 256);
    segsum_multi<<<N, OUT_DIM / 2, 0, stream>>>(Hb, out, off, cnt, eid, srcs, 7, 1, OUT_DIM, 256, 0);
}